// Round 12
// baseline (150.420 us; speedup 1.0000x reference)
//
#include <hip/hip_runtime.h>
#include <math.h>

#define EPS      0.1f
#define INV_EPS  10.0f
#define THRESH   0.1f
#define MAX_IT   20

// Problem sizes (fixed by reference setup_inputs)
#define BB 4
#define NN 1024
#define MM 1024
#define DD 512

#define MU_P (1.0f / 1024.0f + 1e-8f)

// Sinkhorn loop config: 128 blocks x 512 threads, 32 rows/block, 4 rows/wave
#define GBLK 128
#define TBLK 512

// workspace layout (float offsets). No K array: K lives only in each block's LDS.
#define OFF_XB   ((size_t)0)                   // x bf16 [B,N,D] (4 MB)
#define OFF_YB   ((size_t)1048576)             // y bf16 [B,M,D] (4 MB)
#define OFF_NX   ((size_t)2097152)             // |x_i| [B*N]
#define OFF_NY   (OFF_NX + 4096)               // |y_j| [B*M]
#define OFF_NUP  (OFF_NY + 4096)               // nu + 1e-8 [B*M]
#define OFF_CS   (OFF_NUP + 4096)              // colsum rotation [3][4096] (hot!)
#define OFF_FLG  (OFF_CS + 12288)              // barrier flags [2][128] ulong

typedef __bf16 bf16x8 __attribute__((ext_vector_type(8)));
typedef float f32x4 __attribute__((ext_vector_type(4)));
typedef unsigned long long u64;

__device__ __forceinline__ float wave_reduce_sum(float x) {
#pragma unroll
  for (int off = 32; off > 0; off >>= 1) x += __shfl_xor(x, off, 64);
  return x;
}

// pack two floats to bf16x2 (RNE via compiler cast)
__device__ __forceinline__ uint pk2(float a, float b) {
  __bf16 ha = (__bf16)a, hb = (__bf16)b;
  return (uint)*(ushort*)&ha | ((uint)*(ushort*)&hb << 16);
}

// -------- prep: fp32 norms (from ORIGINAL fp32), x/y -> bf16, state init --------
// Unchanged from round 11 (verified): kernel boundary makes xb/yb/norms/zeros
// visible device-wide to the cooperative kernel.
__global__ void __launch_bounds__(256) prep_kernel(const float* __restrict__ x,
                                                   const float* __restrict__ y,
                                                   ushort* __restrict__ xb,
                                                   ushort* __restrict__ yb,
                                                   float* __restrict__ nx,
                                                   float* __restrict__ ny,
                                                   const float* __restrict__ nu,
                                                   float* nup, float* colsum,
                                                   int* flagsi, float* out) {
  const int tid = threadIdx.x;
  int gt = blockIdx.x * 256 + tid;
  if (gt < BB * MM) {
    nup[gt] = nu[gt] + 1e-8f;
    colsum[4096 + gt] = 0.f;      // colsum[1] is iteration 0's add target
  }
  if (gt < 512) flagsi[gt] = 0;   // 2 x 128 ulong flag slots
  if (gt < BB) out[gt] = 0.f;

  const int w = tid >> 6, lane = tid & 63;
  const int r = blockIdx.x * 4 + w;              // 0..8191
  const bool isx = (r < BB * NN);
  const float* src = isx ? (x + (size_t)r * DD)
                         : (y + (size_t)(r - BB * NN) * DD);
  ushort* dst = isx ? (xb + (size_t)r * DD)
                    : (yb + (size_t)(r - BB * NN) * DD);
  const float4* s4 = (const float4*)src;
  float4 a = s4[lane * 2];
  float4 b = s4[lane * 2 + 1];
  float ss = a.x * a.x + a.y * a.y + a.z * a.z + a.w * a.w +
             b.x * b.x + b.y * b.y + b.z * b.z + b.w * b.w;
  uint4 pk = make_uint4(pk2(a.x, a.y), pk2(a.z, a.w), pk2(b.x, b.y), pk2(b.z, b.w));
  *(uint4*)(dst + lane * 8) = pk;
  ss = wave_reduce_sum(ss);
  if (lane == 0) {
    float n = sqrtf(ss);
    if (isx) nx[r] = n; else ny[r - BB * NN] = n;
  }
}

__device__ __forceinline__ void unpack8(uint4 k, float* kf) {
  kf[0] = __uint_as_float(k.x << 16);
  kf[1] = __uint_as_float(k.x & 0xffff0000u);
  kf[2] = __uint_as_float(k.y << 16);
  kf[3] = __uint_as_float(k.y & 0xffff0000u);
  kf[4] = __uint_as_float(k.z << 16);
  kf[5] = __uint_as_float(k.z & 0xffff0000u);
  kf[6] = __uint_as_float(k.w << 16);
  kf[7] = __uint_as_float(k.w & 0xffff0000u);
}

__device__ __forceinline__ float agl(const float* p) {
  return __hip_atomic_load(p, __ATOMIC_RELAXED, __HIP_MEMORY_SCOPE_AGENT);
}

// -------- fused persistent kernel: MFMA K-phase + Sinkhorn loop + cost --------
// Phase B: block computes its OWN 32x1024 K-slab straight into LDS Kt via
// 16x16x32 bf16 MFMA (A = own x rows, L1-resident; B = batch y rows, direct
// global fragment loads). Same fragment layout + epilogue math as the verified
// standalone gemm -> bitwise-identical K. acc kept to 2x4 frags (32 VGPRs) with
// two n-halves so the kernel fits the 64-VGPR compile budget without spilling.
// Loop + final: verbatim round 11 (measured good).
__global__ void __launch_bounds__(TBLK) sinkhorn_kernel(
    const ushort* __restrict__ xb, const ushort* __restrict__ yb,
    const float* __restrict__ nxg, const float* __restrict__ nyg,
    float* __restrict__ colsum, const float* __restrict__ nup,
    u64* __restrict__ flags, float* __restrict__ out) {
  const int tid = threadIdx.x;
  const int bid = blockIdx.x;
  const int lane = tid & 63;
  const int w = tid >> 6;                 // 0..7
  const int b = bid >> 5;                 // batch (32 blocks per batch)
  const int rbase = (bid & 31) * 32;      // first owned row within batch

  __shared__ ushort Kt[32 * 1024];        // 64 KB: this block's K rows (bf16)
  __shared__ float swv[1024];             // ny during phase B, wv during loop
  __shared__ float spart[8][1024];        // 32 KB per-wave column partials
  __shared__ float s_nx[32];
  __shared__ float s_red;
  __shared__ int s_conv;

  // ---- phase B: compute Kt = exp(-(1 - dot/den)/eps) for own 32 rows ----
  {
    const int m16 = lane & 15, q = lane >> 4;
    // stage ny (all 1024 of batch) into swv; own 32 nx into s_nx
    swv[tid] = nyg[b * MM + tid];
    swv[tid + 512] = nyg[b * MM + tid + 512];
    if (tid < 32) s_nx[tid] = nxg[b * NN + rbase + tid];
    __syncthreads();

    const ushort* xrow = xb + ((size_t)b * NN + rbase) * DD;
    const ushort* yrow = yb + ((size_t)b * MM) * DD;

#pragma unroll
    for (int half = 0; half < 2; ++half) {
      f32x4 acc[2][4];
#pragma unroll
      for (int mi = 0; mi < 2; ++mi)
#pragma unroll
        for (int ni = 0; ni < 4; ++ni) acc[mi][ni] = (f32x4)0.f;

      for (int k0 = 0; k0 < DD; k0 += 32) {
        bf16x8 af[2];
#pragma unroll
        for (int mi = 0; mi < 2; ++mi)
          af[mi] = *(const bf16x8*)(xrow + (size_t)(mi * 16 + m16) * DD + k0 + q * 8);
#pragma unroll
        for (int ni = 0; ni < 4; ++ni) {
          const int n = w * 128 + half * 64 + ni * 16 + m16;
          bf16x8 bf = *(const bf16x8*)(yrow + (size_t)n * DD + k0 + q * 8);
          acc[0][ni] = __builtin_amdgcn_mfma_f32_16x16x32_bf16(af[0], bf, acc[0][ni], 0, 0, 0);
          acc[1][ni] = __builtin_amdgcn_mfma_f32_16x16x32_bf16(af[1], bf, acc[1][ni], 0, 0, 0);
        }
      }
      // epilogue into LDS Kt (column-disjoint across waves, no race)
#pragma unroll
      for (int mi = 0; mi < 2; ++mi)
#pragma unroll
        for (int ni = 0; ni < 4; ++ni)
#pragma unroll
          for (int r = 0; r < 4; ++r) {
            const int m = mi * 16 + q * 4 + r;            // local row 0..31
            const int n = w * 128 + half * 64 + ni * 16 + m16;
            float den = fmaxf(s_nx[m] * swv[n], 1e-8f);
            float cv = 1.0f - acc[mi][ni][r] / den;
            float kf = __expf(-cv * INV_EPS);
            __bf16 hb = (__bf16)kf;
            Kt[m * 1024 + n] = *(ushort*)&hb;
          }
    }
  }
  __syncthreads();   // Kt complete; swv free for loop reuse

  const float eps_log_mu = EPS * __logf(MU_P);
  float u_prev[4] = {0.f, 0.f, 0.f, 0.f};
  float wu_reg[4] = {0.f, 0.f, 0.f, 0.f};
  int T = 0;

  for (int it = 0; it < MAX_IT; ++it) {
    const int genv = it + 1;
    // ---- stage wv (local v reconstruction; it=0: v=0 -> wv=1) ----
    if (tid == 0) s_red = 0.f;
    if (it == 0) {
      swv[tid] = 1.f;
      swv[tid + 512] = 1.f;
    } else {
      const float* cs = colsum + (it % 3) * 4096 + b * MM;
      float c0 = agl(cs + tid);
      float c1 = agl(cs + tid + 512);
      swv[tid] = nup[b * MM + tid] / c0;
      swv[tid + 512] = nup[b * MM + tid + 512] / c1;
    }
    __syncthreads();

    float wvr[16];
    {
      const float4* wp = (const float4*)swv;
      *(float4*)&wvr[0] = wp[lane * 2];
      *(float4*)&wvr[4] = wp[lane * 2 + 1];
      *(float4*)&wvr[8] = wp[128 + lane * 2];
      *(float4*)&wvr[12] = wp[129 + lane * 2];
    }
    float creg[16];
#pragma unroll
    for (int t2 = 0; t2 < 16; ++t2) creg[t2] = 0.f;

    float werr = 0.f;
#pragma unroll
    for (int rr = 0; rr < 4; ++rr) {
      const uint4* kp = (const uint4*)(Kt + (w * 4 + rr) * MM);
      uint4 k0 = kp[lane], k1 = kp[lane + 64];   // ds_read_b128, stride-1
      float kf[16];
      unpack8(k0, kf);
      unpack8(k1, kf + 8);
      float s = 0.f;
#pragma unroll
      for (int t2 = 0; t2 < 16; ++t2) s = fmaf(kf[t2], wvr[t2], s);
      s = wave_reduce_sum(s);
      float unv = eps_log_mu - EPS * __logf(s);
      werr += fabsf(unv - u_prev[rr]);
      u_prev[rr] = unv;
      float wu = MU_P / s;          // exp(u_new/eps), exactly
      wu_reg[rr] = wu;
#pragma unroll
      for (int t2 = 0; t2 < 16; ++t2) creg[t2] = fmaf(wu, kf[t2], creg[t2]);
    }
    if (lane == 0) atomicAdd(&s_red, werr);

    // publish per-wave column partials to LDS
    {
      float* pr = &spart[w][0];
      *(float4*)&pr[lane * 8] = *(float4*)&creg[0];
      *(float4*)&pr[lane * 8 + 4] = *(float4*)&creg[4];
      *(float4*)&pr[512 + lane * 8] = *(float4*)&creg[8];
      *(float4*)&pr[512 + lane * 8 + 4] = *(float4*)&creg[12];
    }
    __syncthreads();

    // cross-wave reduce + atomic add into next colsum; zero rotation buffer
    // (rotation keeps the atomic targets HOT in L2/L3 -- cold-buffer atomics
    // were the r8-r10 regression)
    {
      float* csn = colsum + ((it + 1) % 3) * 4096 + b * MM;
      const int j0 = tid * 2;
      float s0 = 0.f, s1 = 0.f;
#pragma unroll
      for (int ww = 0; ww < 8; ++ww) {
        float2 p = *(const float2*)&spart[ww][j0];
        s0 += p.x;
        s1 += p.y;
      }
      unsafeAtomicAdd(&csn[j0], s0);
      unsafeAtomicAdd(&csn[j0 + 1], s1);
      if (tid < 32) {
        float* csz = colsum + ((it + 2) % 3) * 4096;
        __hip_atomic_store(&csz[bid * 32 + tid], 0.f, __ATOMIC_RELAXED, __HIP_MEMORY_SCOPE_AGENT);
      }
    }

    // ---- all-to-all barrier: publish {gen, err}, poll, local conv decision ----
    asm volatile("s_waitcnt vmcnt(0)" ::: "memory");
    __syncthreads();
    if (tid == 0) {
      u64 f = ((u64)(uint)genv << 32) | (u64)__float_as_uint(s_red);
      __hip_atomic_store(&flags[(genv & 1) * GBLK + bid], f, __ATOMIC_RELAXED, __HIP_MEMORY_SCOPE_AGENT);
    }
    if (tid < 64) {
      const u64* fl = flags + (genv & 1) * GBLK;
      u64 f0, f1;
      for (;;) {
        f0 = __hip_atomic_load(fl + tid, __ATOMIC_RELAXED, __HIP_MEMORY_SCOPE_AGENT);
        f1 = __hip_atomic_load(fl + tid + 64, __ATOMIC_RELAXED, __HIP_MEMORY_SCOPE_AGENT);
        if (__all(((f0 >> 32) >= (u64)genv) && ((f1 >> 32) >= (u64)genv))) break;
        __builtin_amdgcn_s_sleep(1);
      }
      float e = __uint_as_float((uint)f0) + __uint_as_float((uint)f1);
      e = wave_reduce_sum(e);
      if (tid == 0) s_conv = (e * (1.0f / (float)BB) < THRESH) ? 1 : 0;
    }
    __syncthreads();
    T = it;
    if (s_conv) break;
  }

  // ---- final: reconstruct converged wv locally, accumulate transport cost ----
  {
    const float* cs = colsum + ((T + 1) % 3) * 4096 + b * MM;
    float c0 = agl(cs + tid);
    float c1 = agl(cs + tid + 512);
    swv[tid] = nup[b * MM + tid] / c0;
    swv[tid + 512] = nup[b * MM + tid + 512] / c1;
  }
  if (tid == 0) s_red = 0.f;
  __syncthreads();

  float wvr[16];
  {
    const float4* wp = (const float4*)swv;
    *(float4*)&wvr[0] = wp[lane * 2];
    *(float4*)&wvr[4] = wp[lane * 2 + 1];
    *(float4*)&wvr[8] = wp[128 + lane * 2];
    *(float4*)&wvr[12] = wp[129 + lane * 2];
  }

  float wcost = 0.f;
#pragma unroll
  for (int rr = 0; rr < 4; ++rr) {
    const uint4* kp = (const uint4*)(Kt + (w * 4 + rr) * MM);
    uint4 k0 = kp[lane], k1 = kp[lane + 64];
    float kf[16];
    unpack8(k0, kf);
    unpack8(k1, kf + 8);
    float s = 0.f;
#pragma unroll
    for (int t2 = 0; t2 < 16; ++t2)
      s = fmaf(kf[t2] * wvr[t2], -EPS * __logf(kf[t2]), s);   // pi*C, C = -eps log K
    s = wave_reduce_sum(s) * wu_reg[rr];
    if (lane == 0) wcost += s;
  }
  if (lane == 0) atomicAdd(&s_red, wcost);
  __syncthreads();
  if (tid == 0) atomicAdd(out + b, s_red);
}

extern "C" void kernel_launch(void* const* d_in, const int* in_sizes, int n_in,
                              void* d_out, int out_size, void* d_ws, size_t ws_size,
                              hipStream_t stream) {
  const float* x = (const float*)d_in[0];
  const float* y = (const float*)d_in[1];
  const float* nu = (const float*)d_in[2];
  float* out = (float*)d_out;
  float* ws = (float*)d_ws;

  ushort* xb = (ushort*)(ws + OFF_XB);
  ushort* yb = (ushort*)(ws + OFF_YB);
  float* nx = ws + OFF_NX;
  float* ny = ws + OFF_NY;
  float* nup = ws + OFF_NUP;
  float* cs = ws + OFF_CS;
  u64* flg = (u64*)(ws + OFF_FLG);

  prep_kernel<<<2048, 256, 0, stream>>>(x, y, xb, yb, nx, ny, nu, nup, cs, (int*)flg, out);

  void* args[] = {(void*)&xb, (void*)&yb, (void*)&nx, (void*)&ny,
                  (void*)&cs, (void*)&nup, (void*)&flg, (void*)&out};
  hipLaunchCooperativeKernel(reinterpret_cast<void*>(&sinkhorn_kernel),
                             dim3(GBLK), dim3(TBLK), args, 0, stream);
}